// Round 13
// baseline (1165.616 us; speedup 1.0000x reference)
//
#include <hip/hip_runtime.h>
#include <math.h>

#define NT 30
#define TT 60
#define S  90
#define NN 48
#define SS (S*S)            // 8100
#define PB 72               // bf16 LDS pitch (144B)

typedef __attribute__((ext_vector_type(8))) short bf16x8;
typedef __attribute__((ext_vector_type(4))) float f32x4;

__device__ __forceinline__ unsigned short f2bf(float f) {
    unsigned u = __float_as_uint(f);
    return (unsigned short)((u + 0x7fffu + ((u >> 16) & 1u)) >> 16);
}
__device__ __forceinline__ float bf2f(unsigned short h) {
    return __uint_as_float(((unsigned)h) << 16);
}

struct CellLds {
    unsigned short elT[96 * PB];
    unsigned short erT[96 * PB];
    float fL[48], fR[48];
    float part[NT][6];
    float alph[NT];
    unsigned short svL[96], svR[96], svO[96];
    float resL[2], resR[2], resO[2];   // [0]=scal(M), [1]=mlog(max alpha)
};

// Compute one full cell (all 30 NTs): svec sums (bf16) + scal + mlog.
// rL/rR: split indices whose left/right operand comes from LDS overrides.
__device__ void cellCompute(int s0, int j, int l,
                            const unsigned short* __restrict__ eruleB,
                            const unsigned short* __restrict__ svec,
                            const float* __restrict__ scal,
                            const float* __restrict__ mlog,
                            int rL, const unsigned short* ovL, float scalL, float mlogL,
                            int rR, const unsigned short* ovR, float scalR, float mlogR,
                            CellLds& L, unsigned short* outSv, float* outRes) {
    const int tid  = threadIdx.x;
    const int lane = tid & 63;
    const int w    = tid >> 6;

    // ---- wave 0: per-split factors ----
    if (w == 0) {
        float msum = -INFINITY, sl = 0.f, sr = 0.f, mrv = 0.f;
        if (lane < l) {
            int cl = s0 * NN + s0 + lane;
            int cr = (s0 + lane + 1) * NN + j;
            float mlv = (lane == rL) ? mlogL : mlog[cl];
            mrv       = (lane == rR) ? mlogR : mlog[cr];
            sl        = (lane == rL) ? scalL : scal[cl];
            sr        = (lane == rR) ? scalR : scal[cr];
            msum = mlv + mrv;
        }
        float v = msum;
        for (int o = 32; o > 0; o >>= 1) v = fmaxf(v, __shfl_down(v, o));
        float M = __shfl(v, 0);
        if (lane == 0) outRes[0] = M;
        if (lane < l) {
            L.fL[lane] = __expf(sl + mrv - M);
            L.fR[lane] = __expf(sr - mrv);
        }
    }
    // ---- zero LDS tiles (all threads) ----
    {
        uint4 z = {0u, 0u, 0u, 0u};
        uint4* z1 = (uint4*)L.elT;
        uint4* z2 = (uint4*)L.erT;
        for (int i = tid; i < 96 * PB / 8; i += 384) { z1[i] = z; z2[i] = z; }
    }
    __syncthreads();

    // ---- stage: ushort4 loads, per-row factor, transposed scalar stores ----
    for (int i = tid; i < l * 24; i += 384) {
        int r = i / 24, x0 = (i - r * 24) * 4;
        const unsigned short* pl = (r == rL) ? (ovL + x0)
                                             : (svec + (s0 * NN + s0 + r) * 96 + x0);
        const unsigned short* pr = (r == rR) ? (ovR + x0)
                                             : (svec + ((s0 + r + 1) * NN + j) * 96 + x0);
        ushort4 a4 = *(const ushort4*)pl;
        ushort4 b4 = *(const ushort4*)pr;
        float fl = L.fL[r], fr = L.fR[r];
        unsigned short* eld = L.elT + x0 * PB + r;
        unsigned short* erd = L.erT + x0 * PB + r;
        eld[0 * PB] = f2bf(bf2f(a4.x) * fl); eld[1 * PB] = f2bf(bf2f(a4.y) * fl);
        eld[2 * PB] = f2bf(bf2f(a4.z) * fl); eld[3 * PB] = f2bf(bf2f(a4.w) * fl);
        erd[0 * PB] = f2bf(bf2f(b4.x) * fr); erd[1 * PB] = f2bf(bf2f(b4.y) * fr);
        erd[2 * PB] = f2bf(bf2f(b4.z) * fr); erd[3 * PB] = f2bf(bf2f(b4.w) * fr);
    }
    __syncthreads();

    // ---- G via MFMA: 6 waves x 6 col-tiles ----
    const int K = (l > 32) ? 64 : 32;
    f32x4 acc[6];
    {
        f32x4 zz = {0.f, 0.f, 0.f, 0.f};
#pragma unroll
        for (int tc = 0; tc < 6; ++tc) acc[tc] = zz;
    }
    const int arow = w * 16 + (lane & 15);
    const int koff = (lane >> 4) * 8;
    for (int ks = 0; ks < (K >> 5); ++ks) {
        bf16x8 af = *(const bf16x8*)(L.elT + arow * PB + ks * 32 + koff);
#pragma unroll
        for (int tc = 0; tc < 6; ++tc) {
            bf16x8 bfr = *(const bf16x8*)(L.erT + (tc * 16 + (lane & 15)) * PB + ks * 32 + koff);
            acc[tc] = __builtin_amdgcn_mfma_f32_16x16x32_bf16(af, bfr, acc[tc], 0, 0, 0);
        }
    }

    // ---- contraction: all 30 a's, wave w owns tile slice w*6..w*6+5 ----
#pragma unroll 2
    for (int a = 0; a < NT; ++a) {
        const unsigned short* rp = eruleB + (a * 36 + w * 6) * 256 + lane * 4;
        float p = 0.f;
#pragma unroll
        for (int tc = 0; tc < 6; ++tc) {
            uint2 rv = *(const uint2*)(rp + tc * 256);
            float r0 = __uint_as_float((rv.x & 0xffffu) << 16);
            float r1 = __uint_as_float(rv.x & 0xffff0000u);
            float r2 = __uint_as_float((rv.y & 0xffffu) << 16);
            float r3 = __uint_as_float(rv.y & 0xffff0000u);
            p += r0 * acc[tc][0] + r1 * acc[tc][1]
               + r2 * acc[tc][2] + r3 * acc[tc][3];
        }
        for (int o = 32; o > 0; o >>= 1) p += __shfl_down(p, o);
        if (lane == 0) L.part[a][w] = p;
    }
    __syncthreads();

    // ---- finalize: sums -> outSv, scal/mlog -> outRes ----
    if (tid < NT) {
        float s = L.part[tid][0] + L.part[tid][1] + L.part[tid][2]
                + L.part[tid][3] + L.part[tid][4] + L.part[tid][5];
        L.alph[tid] = s;
        outSv[tid] = f2bf(s);
    }
    if (tid >= NT && tid < 96) outSv[tid] = 0;
    __syncthreads();
    if (w == 0) {
        float s = (lane < NT) ? L.alph[lane] : -INFINITY;
        for (int o = 32; o > 0; o >>= 1) s = fmaxf(s, __shfl_down(s, o));
        if (lane == 0) outRes[1] = outRes[0] + logf(s);
    }
    __syncthreads();
}

// One prep kernel: blocks 0..1079 write bf16 tile-major erule (no max-shift);
// blocks 1080..1127 init diag svec/scal/mlog.
__global__ void k_prep(const float* __restrict__ rule, const float* __restrict__ unary,
                       unsigned short* __restrict__ eruleB, unsigned short* __restrict__ svec,
                       float* __restrict__ scal, float* __restrict__ mlog) {
    const int b    = blockIdx.x;
    const int lane = threadIdx.x;   // 64
    if (b < 1080) {
        const int a = b / 36, tIdx = b - a * 36;
        const int bt = tIdx / 6, ct = tIdx - bt * 6;
        ushort4 vv;
        unsigned short* pv = (unsigned short*)&vv;
#pragma unroll
        for (int reg = 0; reg < 4; ++reg) {
            int bb = bt * 16 + (lane >> 4) * 4 + reg;
            int cc = ct * 16 + (lane & 15);
            float val = (bb < S && cc < S) ? __expf(rule[a * SS + bb * S + cc]) : 0.f;
            pv[reg] = f2bf(val);
        }
        *(ushort4*)(eruleB + ((a * 36 + tIdx) * 64 + lane) * 4) = vv;
    } else {
        const int i = b - 1080;
        float u = (lane < TT) ? unary[i * TT + lane] : -INFINITY;
        float m = u;
        for (int o = 32; o > 0; o >>= 1) m = fmaxf(m, __shfl_down(m, o));
        m = __shfl(m, 0);
        for (int t = lane; t < 96; t += 64)
            svec[(i * NN + i) * 96 + t] =
                (t >= NT && t < S) ? f2bf(__expf(unary[i * TT + (t - NT)] - m)) : (unsigned short)0;
        if (lane == 0) { scal[i * NN + i] = m; mlog[i * NN + i] = m; }
    }
}

// Merged kernel: role-A blocks compute level lA cells; role-B blocks compute
// level lA+1 cells, recomputing their two level-lA dependencies inline.
__global__ __launch_bounds__(384, 1) void k_pair(int lA,
                                                 const unsigned short* __restrict__ eruleB,
                                                 unsigned short* __restrict__ svec,
                                                 float* __restrict__ scal,
                                                 float* __restrict__ mlog) {
    __shared__ CellLds L;
    const int tid = threadIdx.x;
    const int nA  = NN - lA;

    int cell;
    if ((int)blockIdx.x < nA) {
        // ---- role A: level lA, direct ----
        const int s0 = blockIdx.x;
        const int j  = s0 + lA;
        cell = s0 * NN + j;
        cellCompute(s0, j, lA, eruleB, svec, scal, mlog,
                    -1, nullptr, 0.f, 0.f, -1, nullptr, 0.f, 0.f,
                    L, L.svO, L.resO);
    } else {
        // ---- role B: level lB = lA+1, recompute 2 level-lA deps ----
        const int s0 = blockIdx.x - nA;
        const int lB = lA + 1;
        const int j  = s0 + lB;
        cell = s0 * NN + j;
        // recompute left dep (s0, s0+lA)
        cellCompute(s0, s0 + lA, lA, eruleB, svec, scal, mlog,
                    -1, nullptr, 0.f, 0.f, -1, nullptr, 0.f, 0.f,
                    L, L.svL, L.resL);
        // recompute right dep (s0+1, s0+1+lA)
        cellCompute(s0 + 1, s0 + 1 + lA, lA, eruleB, svec, scal, mlog,
                    -1, nullptr, 0.f, 0.f, -1, nullptr, 0.f, 0.f,
                    L, L.svR, L.resR);
        // own cell: split m=lA uses svL as left; split m=0 uses svR as right
        cellCompute(s0, j, lB, eruleB, svec, scal, mlog,
                    lA, L.svL, L.resL[0], L.resL[1],
                    0,  L.svR, L.resR[0], L.resR[1],
                    L, L.svO, L.resO);
    }
    // ---- write the real cell ----
    if (tid < 96) svec[cell * 96 + tid] = L.svO[tid];
    if (tid == 0) { scal[cell] = L.resO[0]; mlog[cell] = L.resO[1]; }
}

__global__ void k_final(const float* __restrict__ root, const unsigned short* __restrict__ svec,
                        const float* __restrict__ scal, float* __restrict__ out) {
    const int t = threadIdx.x;  // 64
    const int cell = NN - 1;    // (0, 47)
    float v = (t < NT) ? scal[cell] + logf(bf2f(svec[cell * 96 + t])) + root[t] : -INFINITY;
    float m = v;
    for (int o = 32; o > 0; o >>= 1) m = fmaxf(m, __shfl_down(m, o));
    m = __shfl(m, 0);
    float e = (t < NT) ? __expf(v - m) : 0.f;
    for (int o = 32; o > 0; o >>= 1) e += __shfl_down(e, o);
    if (t == 0) out[0] = m + logf(e);
}

extern "C" void kernel_launch(void* const* d_in, const int* in_sizes, int n_in,
                              void* d_out, int out_size, void* d_ws, size_t ws_size,
                              hipStream_t stream) {
    const float* unary = (const float*)d_in[0];  // (48,60)
    const float* rule  = (const float*)d_in[1];  // (30,90,90)
    const float* root  = (const float*)d_in[2];  // (30,)
    float* out = (float*)d_out;

    float*          ws     = (float*)d_ws;
    unsigned short* eruleB = (unsigned short*)ws;           // 276480 ushorts
    unsigned short* svec   = eruleB + 30 * 36 * 256;        // 221184 ushorts
    float*          scal   = (float*)(svec + NN * NN * 96); // 2304 floats
    float*          mlog   = scal + NN * NN;                // 2304 floats

    k_prep<<<1128, 64, 0, stream>>>(rule, unary, eruleB, svec, scal, mlog);
    for (int lA = 1; lA < NN; lA += 2) {
        int nA = NN - lA;
        int nB = (lA + 1 < NN) ? NN - (lA + 1) : 0;
        k_pair<<<nA + nB, 384, 0, stream>>>(lA, eruleB, svec, scal, mlog);
    }
    k_final<<<1, 64, 0, stream>>>(root, svec, scal, out);
}

// Round 14
// 300.156 us; speedup vs baseline: 3.8834x; 3.8834x over previous
//
#include <hip/hip_runtime.h>
#include <math.h>

#define NT 30
#define TT 60
#define S  90
#define NN 48
#define SS (S*S)            // 8100
#define PB 72               // bf16 LDS pitch (144B, 16B-aligned rows)

typedef __attribute__((ext_vector_type(8))) short bf16x8;
typedef __attribute__((ext_vector_type(4))) float f32x4;

__device__ __forceinline__ unsigned ordKey(float f) {
    unsigned u = __float_as_uint(f);
    return (u & 0x80000000u) ? ~u : (u | 0x80000000u);
}
__device__ __forceinline__ float decKey(unsigned k) {
    unsigned u = (k & 0x80000000u) ? (k ^ 0x80000000u) : ~k;
    return __uint_as_float(u);
}
__device__ __forceinline__ unsigned short f2bf(float f) {
    unsigned u = __float_as_uint(f);
    return (unsigned short)((u + 0x7fffu + ((u >> 16) & 1u)) >> 16);
}
__device__ __forceinline__ float bf2f(unsigned short h) {
    return __uint_as_float(((unsigned)h) << 16);
}

// One prep kernel, 1128 blocks x 64:
//   blocks 0..1079: bf16 tile-major erule (no max shift needed: exp(rule) in range)
//   blocks 1080..1127: diag cell init (svec/scal/mkey row)
//   all blocks: grid-stride zero of non-diag svec; block 0 zeros facc/fdone.
__global__ void k_prep(const float* __restrict__ rule, const float* __restrict__ unary,
                       unsigned short* __restrict__ eruleB, unsigned short* __restrict__ svec,
                       float* __restrict__ scal, unsigned* __restrict__ mkey,
                       float* __restrict__ facc, unsigned* __restrict__ fdone) {
    const int b    = blockIdx.x;
    const int lane = threadIdx.x;   // 64

    // grid-stride zero of svec (skip diag cells, they are written below)
    unsigned* usv = (unsigned*)svec;                 // 48 uints per cell
    for (int u = b * 64 + lane; u < NN * NN * 48; u += 1128 * 64) {
        int cellIdx = u / 48;
        int i = cellIdx / NN, jj = cellIdx - i * NN;
        if (i != jj) usv[u] = 0u;
    }
    if (b == 0 && lane == 0) { facc[0] = 0.f; fdone[0] = 0u; }

    if (b < 1080) {
        const int a = b / 36, tIdx = b - a * 36;
        const int bt = tIdx / 6, ct = tIdx - bt * 6;
        ushort4 vv;
        unsigned short* pv = (unsigned short*)&vv;
#pragma unroll
        for (int reg = 0; reg < 4; ++reg) {
            int bb = bt * 16 + (lane >> 4) * 4 + reg;
            int cc = ct * 16 + (lane & 15);
            float val = (bb < S && cc < S) ? __expf(rule[a * SS + bb * S + cc]) : 0.f;
            pv[reg] = f2bf(val);
        }
        *(ushort4*)(eruleB + ((a * 36 + tIdx) * 64 + lane) * 4) = vv;
    } else {
        const int i = b - 1080;
        float u = (lane < TT) ? unary[i * TT + lane] : -INFINITY;
        float m = u;
        for (int o = 32; o > 0; o >>= 1) m = fmaxf(m, __shfl_down(m, o));
        m = __shfl(m, 0);
        for (int t = lane; t < 96; t += 64)
            svec[(i * NN + i) * 96 + t] =
                (t >= NT && t < S) ? f2bf(__expf(unary[i * TT + (t - NT)] - m)) : (unsigned short)0;
        if (lane == 0) scal[i * NN + i] = m;
        if (lane < NN) mkey[i * NN + lane] = (lane == i) ? ordKey(m) : 0u;
    }
}

// grid (NN-l, 30): one block per (span, nonterminal).
// At l == NN-1 the 30 blocks of the single cell also produce out[0].
__global__ __launch_bounds__(384, 1) void k_level(int l,
                                                  const unsigned short* __restrict__ eruleB,
                                                  unsigned short* __restrict__ svec,
                                                  float* __restrict__ scal,
                                                  unsigned* __restrict__ mkey,
                                                  const float* __restrict__ root,
                                                  float* __restrict__ facc,
                                                  unsigned* __restrict__ fdone,
                                                  float* __restrict__ out) {
    const int s0   = blockIdx.x;
    const int a    = blockIdx.y;
    const int j    = s0 + l;
    const int cell = s0 * NN + j;
    const int tid  = threadIdx.x;
    const int lane = tid & 63;
    const int w    = tid >> 6;

    __shared__ unsigned short elT[96 * PB];
    __shared__ unsigned short erT[96 * PB];
    __shared__ float fLs[48], fRs[48];
    __shared__ float part[6];
    __shared__ float Msh;

    // ---- prefetch erule tiles for this (a, wave) into registers (independent) ----
    uint2 rv[6];
    {
        const unsigned short* rp = eruleB + (a * 36 + w * 6) * 256 + lane * 4;
#pragma unroll
        for (int tc = 0; tc < 6; ++tc) rv[tc] = *(const uint2*)(rp + tc * 256);
    }

    // ---- wave 0: per-split factors; waves 1-5: zero LDS tiles ----
    if (w == 0) {
        float msum = -INFINITY, sl = 0.f, sr = 0.f, mrv = 0.f;
        if (lane < l) {
            int cl = s0 * NN + s0 + lane;
            int cr = (s0 + lane + 1) * NN + j;
            float mlv = decKey(mkey[cl]);
            mrv = decKey(mkey[cr]);
            sl = scal[cl]; sr = scal[cr];
            msum = mlv + mrv;
        }
        float v = msum;
        for (int o = 32; o > 0; o >>= 1) v = fmaxf(v, __shfl_down(v, o));
        float M = __shfl(v, 0);
        if (lane == 0) Msh = M;
        if (lane < l) {
            fLs[lane] = __expf(sl + mrv - M);
            fRs[lane] = __expf(sr - mrv);
        }
    } else {
        uint4 z = {0u, 0u, 0u, 0u};
        uint4* z1 = (uint4*)elT;
        uint4* z2 = (uint4*)erT;
        for (int i = tid - 64; i < 96 * PB / 8; i += 320) { z1[i] = z; z2[i] = z; }
    }
    __syncthreads();

    // ---- stage: 4 K-rows per lane, ushort4 LDS stores ----
    const int gmax = (l + 3) >> 2;
    for (int i = tid; i < gmax * S; i += 384) {
        int g = i / S, x = i - g * S;
        int r0 = g * 4;
        const unsigned short* pl = svec + (s0 * NN + s0 + r0) * 96 + x;        // +96 per row
        const unsigned short* pr = svec + ((s0 + r0 + 1) * NN + j) * 96 + x;   // +NN*96 per row
        ushort4 lv, rv4;
        unsigned short* plv = (unsigned short*)&lv;
        unsigned short* prv = (unsigned short*)&rv4;
#pragma unroll
        for (int k = 0; k < 4; ++k) {
            int r = r0 + k;
            plv[k] = (r < l) ? f2bf(bf2f(pl[k * 96]) * fLs[r]) : (unsigned short)0;
            prv[k] = (r < l) ? f2bf(bf2f(pr[k * (NN * 96)]) * fRs[r]) : (unsigned short)0;
        }
        *(ushort4*)(elT + x * PB + r0) = lv;
        *(ushort4*)(erT + x * PB + r0) = rv4;
    }
    __syncthreads();

    // ---- G via MFMA: 6 waves x 6 col-tiles ----
    const int K = (l > 32) ? 64 : 32;
    f32x4 acc[6];
    {
        f32x4 zz = {0.f, 0.f, 0.f, 0.f};
#pragma unroll
        for (int tc = 0; tc < 6; ++tc) acc[tc] = zz;
    }
    const int arow = w * 16 + (lane & 15);
    const int koff = (lane >> 4) * 8;
    for (int ks = 0; ks < (K >> 5); ++ks) {
        bf16x8 af = *(const bf16x8*)(elT + arow * PB + ks * 32 + koff);
#pragma unroll
        for (int tc = 0; tc < 6; ++tc) {
            bf16x8 bfr = *(const bf16x8*)(erT + (tc * 16 + (lane & 15)) * PB + ks * 32 + koff);
            acc[tc] = __builtin_amdgcn_mfma_f32_16x16x32_bf16(af, bfr, acc[tc], 0, 0, 0);
        }
    }

    // ---- contraction from prefetched registers ----
    float p = 0.f;
#pragma unroll
    for (int tc = 0; tc < 6; ++tc) {
        float r0 = __uint_as_float((rv[tc].x & 0xffffu) << 16);
        float r1 = __uint_as_float(rv[tc].x & 0xffff0000u);
        float r2 = __uint_as_float((rv[tc].y & 0xffffu) << 16);
        float r3 = __uint_as_float(rv[tc].y & 0xffff0000u);
        p += r0 * acc[tc][0] + r1 * acc[tc][1]
           + r2 * acc[tc][2] + r3 * acc[tc][3];
    }
    for (int o = 32; o > 0; o >>= 1) p += __shfl_down(p, o);
    if (lane == 0) part[w] = p;
    __syncthreads();

    // ---- finalize ----
    if (tid == 0) {
        float sum = part[0] + part[1] + part[2] + part[3] + part[4] + part[5];
        if (l == NN - 1) {
            // top cell: 30 blocks reduce the root logsumexp via atomics
            atomicAdd(facc, sum * __expf(root[a]));
            __threadfence();
            unsigned old = atomicAdd(fdone, 1u);
            if (old == 29u) out[0] = Msh + logf(atomicAdd(facc, 0.0f));
        } else {
            float alpha = Msh + logf(sum);
            svec[cell * 96 + a] = f2bf(sum);
            if (a == 0) scal[cell] = Msh;
            atomicMax(&mkey[cell], ordKey(alpha));
        }
    }
}

extern "C" void kernel_launch(void* const* d_in, const int* in_sizes, int n_in,
                              void* d_out, int out_size, void* d_ws, size_t ws_size,
                              hipStream_t stream) {
    const float* unary = (const float*)d_in[0];  // (48,60)
    const float* rule  = (const float*)d_in[1];  // (30,90,90)
    const float* root  = (const float*)d_in[2];  // (30,)
    float* out = (float*)d_out;

    float*          ws     = (float*)d_ws;
    unsigned short* eruleB = (unsigned short*)ws;           // 276480 ushorts
    unsigned short* svec   = eruleB + 30 * 36 * 256;        // 221184 ushorts
    float*          scal   = (float*)(svec + NN * NN * 96); // 2304 floats
    unsigned*       mkey   = (unsigned*)(scal + NN * NN);   // 2304
    float*          facc   = (float*)(mkey + NN * NN);      // 1
    unsigned*       fdone  = (unsigned*)(facc + 1);         // 1

    k_prep<<<1128, 64, 0, stream>>>(rule, unary, eruleB, svec, scal, mkey, facc, fdone);
    for (int l = 1; l < NN; ++l) {
        k_level<<<dim3(NN - l, 30), 384, 0, stream>>>(l, eruleB, svec, scal, mkey,
                                                      root, facc, fdone, out);
    }
}